// Round 10
// baseline (1045.170 us; speedup 1.0000x reference)
//
#include <hip/hip_runtime.h>

// LSTMPricePredictor: B=4096, T=512, IN=1, H=50, 2 layers + FC(50->1)
// R10: cross-block overlap + vectorized gate reads.
//   R9 (867 us): VALU issue stuck at ~2475 cyc/SIMD/step across R8->R9;
//   conflicts constant 6.0e7 (the 4x scalar ds_read_b32 gate reads, CP=19);
//   occupancy capped at 47% (grid=256 = 1 block/CU).
//   (a) NROW=8, 512 blocks x 1024 threads -> 2 blocks/CU (32 waves): one
//       block's EW chain overlaps the other's GEMM chain.
//   (b) C buffer re-laid out gate-innermost: Cg[layer][k][m][gate], k-pitch
//       68 words (16B aligned, bank-spread) -> EW reads its 4 gates as ONE
//       ds_read_b128 (2-way aliasing = free); <=1 cell/layer/thread.
// Pipeline semantics identical to R8/R9 (both passed, absmax 4.9e-4):
//   iter u: GEMM gates0^(u) (skip u=TT) + gates1^(u-1) (skip u=0); EW both.

typedef _Float16 half8 __attribute__((ext_vector_type(8)));
typedef float    f32x4 __attribute__((ext_vector_type(4)));

#define TT   512
#define HID  50
#define NG   200        // 4*H
#define NROW 8          // batch rows per block (M=16 frame, rows 8..15 zero)
#define KP   68         // k-pitch (words) of gate-vectorized C buffer

__device__ __forceinline__ float sigm(float v)  { return 1.0f / (1.0f + __expf(-v)); }
__device__ __forceinline__ float tanhh(float v) { return 1.0f - 2.0f / (1.0f + __expf(2.0f * v)); }

// B-fragment (lane's 8 fp16) for tile column n, K-chunk `chunk`.
// B[kk][n] = W[n*50+kk] for kk<50; layer-0 folds W_ih0 at kk==50 (x slot).
__device__ __forceinline__ float4 make_frag(const float* W, const float* Wx,
                                            int n, int chunk, int lane, bool foldx) {
    half8 hv = {};
    #pragma unroll
    for (int j = 0; j < 8; ++j) {
        const int kk = 32 * chunk + 8 * (lane >> 4) + j;
        float v = 0.0f;
        if (n < NG) {
            if (kk < HID)                v = W[n * HID + kk];
            else if (foldx && kk == HID) v = Wx[n];
        }
        hv[j] = (_Float16)v;
    }
    return __builtin_bit_cast(float4, hv);
}

#define PIN(f) asm volatile("" : "+v"(f.x), "+v"(f.y), "+v"(f.z), "+v"(f.w));
#define MFMA(a, bf, c) __builtin_amdgcn_mfma_f32_16x16x32_f16((a), __builtin_bit_cast(half8, (bf)), (c), 0, 0, 0)

extern "C" __global__ __launch_bounds__(1024, 8)
void lstm2_mfma_kernel(const float* __restrict__ x,
                       const float* __restrict__ W_ih0, const float* __restrict__ W_hh0,
                       const float* __restrict__ b_ih0, const float* __restrict__ b_hh0,
                       const float* __restrict__ W_ih1, const float* __restrict__ W_hh1,
                       const float* __restrict__ b_ih1, const float* __restrict__ b_hh1,
                       const float* __restrict__ fc_w, const float* __restrict__ fc_b,
                       float* __restrict__ out)
{
    __shared__ _Float16 Ah0[1024];          // h0 (k<50) + x slot (k=50); M=16 frame
    __shared__ _Float16 Ah1[1024];          // h1 (k<50)
    __shared__ float    Cg[2 * HID * KP];   // [layer][k][m][gate], word=k*KP+4*m+gate
    __shared__ float    hfin[HID * NROW];   // final h1 (fp32) for the FC

    const int tid  = threadIdx.x;
    const int lane = tid & 63;
    const int wv   = tid >> 6;                 // wave 0..15
    const int b0   = blockIdx.x * NROW;

    Ah0[tid] = (_Float16)0.f;
    Ah1[tid] = (_Float16)0.f;

    // ---- per-wave B fragments: ONE 16-wide N-tile per wave ----
    const int n0 = 16 * wv;
    const int nA = n0 + (lane & 15);
    const bool tile_on = (n0 < 208);           // waves 13..15 idle in GEMM

    float4 B0A0 = make_frag(W_hh0, W_ih0, nA, 0, lane, true);
    float4 B0A1 = make_frag(W_hh0, W_ih0, nA, 1, lane, true);
    float4 BiA0 = make_frag(W_ih1, W_ih1, nA, 0, lane, false);
    float4 BiA1 = make_frag(W_ih1, W_ih1, nA, 1, lane, false);
    float4 BhA0 = make_frag(W_hh1, W_hh1, nA, 0, lane, false);
    float4 BhA1 = make_frag(W_hh1, W_hh1, nA, 1, lane, false);
    PIN(B0A0) PIN(B0A1) PIN(BiA0) PIN(BiA1) PIN(BhA0) PIN(BhA1)

    const float bias0 = (nA < NG) ? b_ih0[nA] + b_hh0[nA] : 0.f;
    const float bias1 = (nA < NG) ? b_ih1[nA] + b_hh1[nA] : 0.f;

    // C-store target: column nA -> cell-k = nA%50, gate = nA/50
    const int  kcol = nA % HID;
    const int  gcol = nA / HID;
    const int  mr   = 4 * (lane >> 4);
    const bool stv  = tile_on && (nA < NG);
    float* C0p = Cg + kcol * KP + gcol;             // + 4*m
    float* C1p = Cg + HID * KP + kcol * KP + gcol;  // layer-1 half

    // x_0 into the x slot (cell (m, k=50): chunk1, lane'=32+m, j=2)
    if (tid < NROW) Ah0[512 + (32 + tid) * 8 + 2] = (_Float16)x[(size_t)(b0 + tid) * TT];

    // ---- EW cell ownership: <=1 cell per layer per thread ----
    // layer-0: threads 0..399    -> (k0=t>>3, m0=t&7)
    // layer-1: threads 624..1023 -> j=t-624, (k1=j>>3, m1=j&7)
    const bool ew0 = (tid < NROW * HID);
    const int  k0 = tid >> 3, m0 = tid & 7;
    const int  j1 = tid - (1024 - NROW * HID);
    const bool ew1 = (j1 >= 0);
    const int  k1 = j1 >> 3, m1 = j1 & 7;
    float c0 = 0.f, c1 = 0.f;

    __syncthreads();

    for (int u = 0; u <= TT; ++u) {
        // ================= GEMM phase =================
        if (tile_on) {
            half8 a00 = *(half8*)(Ah0 + lane * 8);
            half8 a01 = *(half8*)(Ah0 + 512 + lane * 8);
            if (u != TT) {   // layer-0: gates0^(u)
                f32x4 acc = {bias0, bias0, bias0, bias0};
                acc = MFMA(a00, B0A0, acc);
                acc = MFMA(a01, B0A1, acc);
                if (stv) {
                    #pragma unroll
                    for (int r = 0; r < 4; ++r) C0p[4 * (mr + r)] = acc[r];
                }
            }
            if (u != 0) {    // layer-1: gates1^(u-1)
                half8 a10 = *(half8*)(Ah1 + lane * 8);
                half8 a11 = *(half8*)(Ah1 + 512 + lane * 8);
                f32x4 acc = {bias1, bias1, bias1, bias1};
                acc = MFMA(a00, BiA0, acc);
                acc = MFMA(a01, BiA1, acc);
                acc = MFMA(a10, BhA0, acc);
                acc = MFMA(a11, BhA1, acc);
                if (stv) {
                    #pragma unroll
                    for (int r = 0; r < 4; ++r) C1p[4 * (mr + r)] = acc[r];
                }
            }
        }
        __syncthreads();

        // ================= EW phase =================
        float xr = 0.f;
        if (tid < NROW && (u + 1) < TT)
            xr = x[(size_t)(b0 + tid) * TT + u + 1];   // issue global load early

        if (u != TT && ew0) {   // layer-0 update -> h0^(u+1)
            const float4 z = *(const float4*)(Cg + k0 * KP + 4 * m0);  // i,f,g,o
            c0 = sigm(z.y) * c0 + sigm(z.x) * tanhh(z.z);
            const float h = sigm(z.w) * tanhh(c0);
            const int klo = k0 & 31;
            Ah0[(k0 >> 5) * 512 + (((klo >> 3) << 4) + m0) * 8 + (klo & 7)] = (_Float16)h;
        }
        if (u != 0 && ew1) {    // layer-1 update -> h1^(u)
            const float4 z = *(const float4*)(Cg + HID * KP + k1 * KP + 4 * m1);
            c1 = sigm(z.y) * c1 + sigm(z.x) * tanhh(z.z);
            const float h = sigm(z.w) * tanhh(c1);
            const int klo = k1 & 31;
            Ah1[(k1 >> 5) * 512 + (((klo >> 3) << 4) + m1) * 8 + (klo & 7)] = (_Float16)h;
            hfin[k1 * NROW + m1] = h;
        }
        if (tid < NROW && (u + 1) < TT)
            Ah0[512 + (32 + tid) * 8 + 2] = (_Float16)xr;   // x_{u+1} slot
        __syncthreads();
    }

    // ---------- FC epilogue: out[b] = fc_b + fc_w . h1^(TT)[b,:] ----------
    if (tid < NROW) {
        float s = fc_b[0];
        for (int k = 0; k < HID; ++k)
            s += fc_w[k] * hfin[k * NROW + tid];
        out[b0 + tid] = s;
    }
}

extern "C" void kernel_launch(void* const* d_in, const int* in_sizes, int n_in,
                              void* d_out, int out_size, void* d_ws, size_t ws_size,
                              hipStream_t stream) {
    (void)in_sizes; (void)n_in; (void)d_ws; (void)ws_size; (void)out_size;
    const float* x     = (const float*)d_in[0];
    const float* W_ih0 = (const float*)d_in[1];
    const float* W_hh0 = (const float*)d_in[2];
    const float* b_ih0 = (const float*)d_in[3];
    const float* b_hh0 = (const float*)d_in[4];
    const float* W_ih1 = (const float*)d_in[5];
    const float* W_hh1 = (const float*)d_in[6];
    const float* b_ih1 = (const float*)d_in[7];
    const float* b_hh1 = (const float*)d_in[8];
    const float* fc_w  = (const float*)d_in[9];
    const float* fc_b  = (const float*)d_in[10];

    dim3 grid(4096 / NROW);   // 512 blocks -> 2 per CU (32 waves/CU)
    dim3 block(1024);         // 16 waves
    lstm2_mfma_kernel<<<grid, block, 0, stream>>>(
        x, W_ih0, W_hh0, b_ih0, b_hh0,
        W_ih1, W_hh1, b_ih1, b_hh1,
        fc_w, fc_b, (float*)d_out);
}

// Round 11
// 813.893 us; speedup vs baseline: 1.2842x; 1.2842x over previous
//
#include <hip/hip_runtime.h>

// LSTMPricePredictor: B=4096, T=512, IN=1, H=50, 2 layers + FC(50->1)
// R11: TRANSPOSED GEMM -> in-register elementwise. R7-R10's invariant cost
//   was the gates' LDS round-trip (C-store + scalar/vector reads, 6e7-1.7e8
//   bank-conflict cycles). Fix: weights become the A operand (M = gate rows,
//   interleaved row = 4*cell + gate), h becomes the B operand (N = batch).
//   D mapping (row=4*quad+reg, col=lane&15) => one lane's 4 acc regs are
//   exactly i,f,g,o of cell (4*tile+quad) for batch col. EW runs entirely
//   on MFMA outputs; only h (1 fp16/lane) goes back to LDS (B-layout,
//   double-buffered). ONE barrier per step.
// 256 blocks (1/CU) x 832 threads (13 waves). Wave t owns gate rows
//   16t..16t+15 = cells 4t..4t+3 (cells 50,51 pad). NB=16 batch rows/block.
// Iteration u (0..512), buffers H0[2]/H1[2] ping-pong on u&1:
//   L0 (skip u=TT): gates0^u = W0.[h0^u; x_u]   -> EW -> h0^{u+1} -> H0[u+1&1]
//   L1 (skip u=0):  gates1^{u-1} = Wi1.h0^u + Wh1.h1^{u-1} -> EW -> h1^u -> H1[u&1]
// Layout provenance: A[m=lane&15][k=8*quad+j], B[k=8*quad+j][n=lane&15],
//   D[row=4*quad+reg][col=lane&15] -- empirically verified by R7-R10 passes.

typedef _Float16 half8 __attribute__((ext_vector_type(8)));
typedef float    f32x4 __attribute__((ext_vector_type(4)));

#define TT   512
#define HID  50
#define NB   16         // batch rows per block

__device__ __forceinline__ float sigm(float v)  { return 1.0f / (1.0f + __expf(-v)); }
__device__ __forceinline__ float tanhh(float v) { return 1.0f - 2.0f / (1.0f + __expf(2.0f * v)); }

// Weight A-fragment: lane's 8 fp16 for K-chunk `chunk`.
// Row m = lane&15 -> gate = m&3, cell = 4*tile + (m>>2); k = 32*chunk+8*quad+j.
// W is (200 x 50) torch-layout: element [gate*50+cell][k]. Layer-0 folds
// W_ih0 (200 x 1) at k==50 (the x slot).
__device__ __forceinline__ float4 make_wfrag(const float* W, const float* Wx,
                                             int gate, int cell, int chunk,
                                             int quad, bool foldx) {
    half8 hv = {};
    #pragma unroll
    for (int j = 0; j < 8; ++j) {
        const int k = 32 * chunk + 8 * quad + j;
        float v = 0.0f;
        if (cell < HID) {
            if (k < HID)                 v = W[(gate * HID + cell) * HID + k];
            else if (foldx && k == HID)  v = Wx[gate * HID + cell];
        }
        hv[j] = (_Float16)v;
    }
    return __builtin_bit_cast(float4, hv);
}

#define PIN(f) asm volatile("" : "+v"(f.x), "+v"(f.y), "+v"(f.z), "+v"(f.w));
#define MFMA(af, b, c) __builtin_amdgcn_mfma_f32_16x16x32_f16(__builtin_bit_cast(half8, (af)), (b), (c), 0, 0, 0)

extern "C" __global__ __launch_bounds__(832, 4)
void lstm2_mfma_kernel(const float* __restrict__ x,
                       const float* __restrict__ W_ih0, const float* __restrict__ W_hh0,
                       const float* __restrict__ b_ih0, const float* __restrict__ b_hh0,
                       const float* __restrict__ W_ih1, const float* __restrict__ W_hh1,
                       const float* __restrict__ b_ih1, const float* __restrict__ b_hh1,
                       const float* __restrict__ fc_w, const float* __restrict__ fc_b,
                       float* __restrict__ out)
{
    // h-state in B-fragment layout: element (k, n) at chunk(k>>5)*512 +
    // (((k&31)>>3)*16 + n)*8 + (k&7). k<50 = h, k==50 = x slot (H0 only).
    __shared__ _Float16 H0[2][1024];
    __shared__ _Float16 H1[2][1024];
    __shared__ float    hfin[HID * NB];   // fp32 h1 for the FC epilogue

    const int tid  = threadIdx.x;
    const int lane = tid & 63;
    const int wv   = tid >> 6;            // wave 0..12 = gate-row tile
    const int b0   = blockIdx.x * NB;

    for (int i = tid; i < 1024; i += 832) {
        H0[0][i] = (_Float16)0.f; H0[1][i] = (_Float16)0.f;
        H1[0][i] = (_Float16)0.f; H1[1][i] = (_Float16)0.f;
    }

    const int quad = lane >> 4;
    const int col  = lane & 15;           // batch column

    // ---- A-fragments (weights), loaded once, pinned ----
    const int mrow  = lane & 15;          // A-row within tile
    const int gateA = mrow & 3;
    const int cellA = 4 * wv + (mrow >> 2);
    float4 A0c0 = make_wfrag(W_hh0, W_ih0, gateA, cellA, 0, quad, true);
    float4 A0c1 = make_wfrag(W_hh0, W_ih0, gateA, cellA, 1, quad, true);
    float4 Aic0 = make_wfrag(W_ih1, W_ih1, gateA, cellA, 0, quad, false);
    float4 Aic1 = make_wfrag(W_ih1, W_ih1, gateA, cellA, 1, quad, false);
    float4 Ahc0 = make_wfrag(W_hh1, W_hh1, gateA, cellA, 0, quad, false);
    float4 Ahc1 = make_wfrag(W_hh1, W_hh1, gateA, cellA, 1, quad, false);
    PIN(A0c0) PIN(A0c1) PIN(Aic0) PIN(Aic1) PIN(Ahc0) PIN(Ahc1)

    // ---- D-cell ownership: reg = gate, cell = 4*wv + quad, batch = col ----
    const int  cellD = 4 * wv + quad;
    const bool ewok  = (cellD < HID);
    f32x4 bias0, bias1;
    #pragma unroll
    for (int g = 0; g < 4; ++g) {
        bias0[g] = ewok ? b_ih0[g * HID + cellD] + b_hh0[g * HID + cellD] : 0.f;
        bias1[g] = ewok ? b_ih1[g * HID + cellD] + b_hh1[g * HID + cellD] : 0.f;
    }
    // h write-back index in B-layout for (cellD, col)
    const int wi = (cellD >> 5) * 512 + (((cellD & 31) >> 3) * 16 + col) * 8 + (cellD & 7);

    // x_0 into H0[0]'s x slot: k=50 -> chunk1, quad'=2, j=2
    if (tid < NB) H0[0][512 + (32 + tid) * 8 + 2] = (_Float16)x[(size_t)(b0 + tid) * TT];

    float c0 = 0.f, c1 = 0.f;
    __syncthreads();

    for (int u = 0; u <= TT; ++u) {
        const int pu = u & 1, pn = pu ^ 1;

        half8 b0c0 = *(half8*)(&H0[pu][lane * 8]);
        half8 b0c1 = *(half8*)(&H0[pu][512 + lane * 8]);

        float xr = 0.f;
        if (tid < NB && (u + 1) < TT)
            xr = x[(size_t)(b0 + tid) * TT + u + 1];   // issue early

        if (u != TT) {   // ---- layer-0: gates0^u + in-register EW ----
            f32x4 acc = bias0;
            acc = MFMA(A0c0, b0c0, acc);
            acc = MFMA(A0c1, b0c1, acc);
            c0 = sigm(acc[1]) * c0 + sigm(acc[0]) * tanhh(acc[2]);
            const float h = sigm(acc[3]) * tanhh(c0);
            if (ewok) H0[pn][wi] = (_Float16)h;        // h0^{u+1}
        }
        if (u != 0) {    // ---- layer-1: gates1^{u-1} + in-register EW ----
            half8 b1c0 = *(half8*)(&H1[pn][lane * 8]);
            half8 b1c1 = *(half8*)(&H1[pn][512 + lane * 8]);
            f32x4 acc = bias1;
            acc = MFMA(Aic0, b0c0, acc);               // Wi1 . h0^u
            acc = MFMA(Aic1, b0c1, acc);               // (x slot hits zero rows)
            acc = MFMA(Ahc0, b1c0, acc);               // Wh1 . h1^{u-1}
            acc = MFMA(Ahc1, b1c1, acc);
            c1 = sigm(acc[1]) * c1 + sigm(acc[0]) * tanhh(acc[2]);
            const float h = sigm(acc[3]) * tanhh(c1);
            if (ewok) { H1[pu][wi] = (_Float16)h; hfin[cellD * NB + col] = h; }
        }
        if (tid < NB && (u + 1) < TT)
            H0[pn][512 + (32 + tid) * 8 + 2] = (_Float16)xr;   // x_{u+1} slot
        __syncthreads();
    }

    // ---------- FC epilogue: out[b] = fc_b + fc_w . h1^(TT)[b,:] ----------
    if (tid < NB) {
        float s = fc_b[0];
        for (int k = 0; k < HID; ++k)
            s += fc_w[k] * hfin[k * NB + tid];
        out[b0 + tid] = s;
    }
}

extern "C" void kernel_launch(void* const* d_in, const int* in_sizes, int n_in,
                              void* d_out, int out_size, void* d_ws, size_t ws_size,
                              hipStream_t stream) {
    (void)in_sizes; (void)n_in; (void)d_ws; (void)ws_size; (void)out_size;
    const float* x     = (const float*)d_in[0];
    const float* W_ih0 = (const float*)d_in[1];
    const float* W_hh0 = (const float*)d_in[2];
    const float* b_ih0 = (const float*)d_in[3];
    const float* b_hh0 = (const float*)d_in[4];
    const float* W_ih1 = (const float*)d_in[5];
    const float* W_hh1 = (const float*)d_in[6];
    const float* b_ih1 = (const float*)d_in[7];
    const float* b_hh1 = (const float*)d_in[8];
    const float* fc_w  = (const float*)d_in[9];
    const float* fc_b  = (const float*)d_in[10];

    dim3 grid(4096 / NB);   // 256 blocks, 1 per CU
    dim3 block(832);        // 13 waves
    lstm2_mfma_kernel<<<grid, block, 0, stream>>>(
        x, W_ih0, W_hh0, b_ih0, b_hh0,
        W_ih1, W_hh1, b_ih1, b_hh1,
        fc_w, fc_b, (float*)d_out);
}

// Round 12
// 471.414 us; speedup vs baseline: 2.2171x; 1.7265x over previous
//
#include <hip/hip_runtime.h>

// LSTMPricePredictor: B=4096, T=512, IN=1, H=50, 2 layers + FC(50->1)
// R12 = R11 + fast-rcp activations.
//   R11 (814 us, absmax 4.9e-4): transposed GEMM, in-register EW, conflicts
//   down 9x -- but VALU issue stuck at ~2630 cyc/SIMD/step. Hand-count says
//   ~900; the gap is float DIVISION: without fast-math each `1.0f/x` is the
//   full Newton-Raphson div sequence (~8-10 VALU ops), and we do 10 per
//   lane per step. Fix: __builtin_amdgcn_rcpf (1 v_rcp_f32, ~1 ulp --
//   negligible vs existing fp16 rounding).
//   Also: hfin stored only at the final step; unroll-by-2 to constant-fold
//   the ping-pong buffer selects.
// Structure identical to R11: 256 blocks (1/CU) x 832 threads (13 waves);
//   weights = A operand (row = 4*cell + gate), h = B operand (N = batch=16);
//   D[row=4*quad+reg][col] => lane's 4 acc regs = i,f,g,o of its cell/col;
//   only h goes through LDS (double-buffered B-layout); 1 barrier/step.

typedef _Float16 half8 __attribute__((ext_vector_type(8)));
typedef float    f32x4 __attribute__((ext_vector_type(4)));

#define TT   512
#define HID  50
#define NB   16         // batch rows per block

__device__ __forceinline__ float sigm(float v) {
    return __builtin_amdgcn_rcpf(1.0f + __expf(-v));
}
__device__ __forceinline__ float tanhh(float v) {
    return 1.0f - 2.0f * __builtin_amdgcn_rcpf(1.0f + __expf(2.0f * v));
}

// Weight A-fragment: lane's 8 fp16 for K-chunk `chunk`.
// Row m = lane&15 -> gate = m&3, cell = 4*tile + (m>>2); k = 32*chunk+8*quad+j.
// W is (200 x 50): element [gate*50+cell][k]. Layer-0 folds W_ih0 at k==50.
__device__ __forceinline__ float4 make_wfrag(const float* W, const float* Wx,
                                             int gate, int cell, int chunk,
                                             int quad, bool foldx) {
    half8 hv = {};
    #pragma unroll
    for (int j = 0; j < 8; ++j) {
        const int k = 32 * chunk + 8 * quad + j;
        float v = 0.0f;
        if (cell < HID) {
            if (k < HID)                 v = W[(gate * HID + cell) * HID + k];
            else if (foldx && k == HID)  v = Wx[gate * HID + cell];
        }
        hv[j] = (_Float16)v;
    }
    return __builtin_bit_cast(float4, hv);
}

#define PIN(f) asm volatile("" : "+v"(f.x), "+v"(f.y), "+v"(f.z), "+v"(f.w));
#define MFMA(af, b, c) __builtin_amdgcn_mfma_f32_16x16x32_f16(__builtin_bit_cast(half8, (af)), (b), (c), 0, 0, 0)

extern "C" __global__ __launch_bounds__(832, 4)
void lstm2_mfma_kernel(const float* __restrict__ x,
                       const float* __restrict__ W_ih0, const float* __restrict__ W_hh0,
                       const float* __restrict__ b_ih0, const float* __restrict__ b_hh0,
                       const float* __restrict__ W_ih1, const float* __restrict__ W_hh1,
                       const float* __restrict__ b_ih1, const float* __restrict__ b_hh1,
                       const float* __restrict__ fc_w, const float* __restrict__ fc_b,
                       float* __restrict__ out)
{
    // h-state in B-fragment layout: element (k, n) at chunk(k>>5)*512 +
    // (((k&31)>>3)*16 + n)*8 + (k&7). k<50 = h, k==50 = x slot (H0 only).
    __shared__ _Float16 H0[2][1024];
    __shared__ _Float16 H1[2][1024];
    __shared__ float    hfin[HID * NB];   // fp32 h1^(TT) for the FC epilogue

    const int tid  = threadIdx.x;
    const int lane = tid & 63;
    const int wv   = tid >> 6;            // wave 0..12 = gate-row tile
    const int b0   = blockIdx.x * NB;

    for (int i = tid; i < 1024; i += 832) {
        H0[0][i] = (_Float16)0.f; H0[1][i] = (_Float16)0.f;
        H1[0][i] = (_Float16)0.f; H1[1][i] = (_Float16)0.f;
    }

    const int quad = lane >> 4;
    const int col  = lane & 15;           // batch column

    // ---- A-fragments (weights), loaded once, pinned ----
    const int mrow  = lane & 15;          // A-row within tile
    const int gateA = mrow & 3;
    const int cellA = 4 * wv + (mrow >> 2);
    float4 A0c0 = make_wfrag(W_hh0, W_ih0, gateA, cellA, 0, quad, true);
    float4 A0c1 = make_wfrag(W_hh0, W_ih0, gateA, cellA, 1, quad, true);
    float4 Aic0 = make_wfrag(W_ih1, W_ih1, gateA, cellA, 0, quad, false);
    float4 Aic1 = make_wfrag(W_ih1, W_ih1, gateA, cellA, 1, quad, false);
    float4 Ahc0 = make_wfrag(W_hh1, W_hh1, gateA, cellA, 0, quad, false);
    float4 Ahc1 = make_wfrag(W_hh1, W_hh1, gateA, cellA, 1, quad, false);
    PIN(A0c0) PIN(A0c1) PIN(Aic0) PIN(Aic1) PIN(Ahc0) PIN(Ahc1)

    // ---- D-cell ownership: reg = gate, cell = 4*wv + quad, batch = col ----
    const int  cellD = 4 * wv + quad;
    const bool ewok  = (cellD < HID);
    f32x4 bias0, bias1;
    #pragma unroll
    for (int g = 0; g < 4; ++g) {
        bias0[g] = ewok ? b_ih0[g * HID + cellD] + b_hh0[g * HID + cellD] : 0.f;
        bias1[g] = ewok ? b_ih1[g * HID + cellD] + b_hh1[g * HID + cellD] : 0.f;
    }
    // h write-back index in B-layout for (cellD, col)
    const int wi = (cellD >> 5) * 512 + (((cellD & 31) >> 3) * 16 + col) * 8 + (cellD & 7);

    // x_0 into H0[0]'s x slot: k=50 -> chunk1, quad'=2, j=2
    if (tid < NB) H0[0][512 + (32 + tid) * 8 + 2] = (_Float16)x[(size_t)(b0 + tid) * TT];

    float c0 = 0.f, c1 = 0.f;
    __syncthreads();

    #pragma unroll 2
    for (int u = 0; u <= TT; ++u) {
        const int pu = u & 1, pn = pu ^ 1;

        half8 b0c0 = *(half8*)(&H0[pu][lane * 8]);
        half8 b0c1 = *(half8*)(&H0[pu][512 + lane * 8]);

        float xr = 0.f;
        if (tid < NB && (u + 1) < TT)
            xr = x[(size_t)(b0 + tid) * TT + u + 1];   // issue early

        if (u != TT) {   // ---- layer-0: gates0^u + in-register EW ----
            f32x4 acc = bias0;
            acc = MFMA(A0c0, b0c0, acc);
            acc = MFMA(A0c1, b0c1, acc);
            c0 = sigm(acc[1]) * c0 + sigm(acc[0]) * tanhh(acc[2]);
            const float h = sigm(acc[3]) * tanhh(c0);
            if (ewok) H0[pn][wi] = (_Float16)h;        // h0^{u+1}
        }
        if (u != 0) {    // ---- layer-1: gates1^{u-1} + in-register EW ----
            half8 b1c0 = *(half8*)(&H1[pn][lane * 8]);
            half8 b1c1 = *(half8*)(&H1[pn][512 + lane * 8]);
            f32x4 acc = bias1;
            acc = MFMA(Aic0, b0c0, acc);               // Wi1 . h0^u
            acc = MFMA(Aic1, b0c1, acc);               // (x slot hits zero rows)
            acc = MFMA(Ahc0, b1c0, acc);               // Wh1 . h1^{u-1}
            acc = MFMA(Ahc1, b1c1, acc);
            c1 = sigm(acc[1]) * c1 + sigm(acc[0]) * tanhh(acc[2]);
            const float h = sigm(acc[3]) * tanhh(c1);
            if (ewok) {
                H1[pu][wi] = (_Float16)h;              // h1^u
                if (u == TT) hfin[cellD * NB + col] = h;
            }
        }
        if (tid < NB && (u + 1) < TT)
            H0[pn][512 + (32 + tid) * 8 + 2] = (_Float16)xr;   // x_{u+1} slot
        __syncthreads();
    }

    // ---------- FC epilogue: out[b] = fc_b + fc_w . h1^(TT)[b,:] ----------
    if (tid < NB) {
        float s = fc_b[0];
        for (int k = 0; k < HID; ++k)
            s += fc_w[k] * hfin[k * NB + tid];
        out[b0 + tid] = s;
    }
}

extern "C" void kernel_launch(void* const* d_in, const int* in_sizes, int n_in,
                              void* d_out, int out_size, void* d_ws, size_t ws_size,
                              hipStream_t stream) {
    (void)in_sizes; (void)n_in; (void)d_ws; (void)ws_size; (void)out_size;
    const float* x     = (const float*)d_in[0];
    const float* W_ih0 = (const float*)d_in[1];
    const float* W_hh0 = (const float*)d_in[2];
    const float* b_ih0 = (const float*)d_in[3];
    const float* b_hh0 = (const float*)d_in[4];
    const float* W_ih1 = (const float*)d_in[5];
    const float* W_hh1 = (const float*)d_in[6];
    const float* b_ih1 = (const float*)d_in[7];
    const float* b_hh1 = (const float*)d_in[8];
    const float* fc_w  = (const float*)d_in[9];
    const float* fc_b  = (const float*)d_in[10];

    dim3 grid(4096 / NB);   // 256 blocks, 1 per CU
    dim3 block(832);        // 13 waves
    lstm2_mfma_kernel<<<grid, block, 0, stream>>>(
        x, W_ih0, W_hh0, b_ih0, b_hh0,
        W_ih1, W_hh1, b_ih1, b_hh1,
        fc_w, fc_b, (float*)d_out);
}